// Round 1
// baseline (1663.193 us; speedup 1.0000x reference)
//
#include <hip/hip_runtime.h>

#define B_   2
#define L_   2048
#define D_   1024
#define H_   16
#define DH_  64
#define M_TOT (B_ * L_)   // 4096

#define BM 64
#define BN 64
#define BK 16
#define PAD 4

// ---------------------------------------------------------------------------
// NT GEMM: C[M,N] = A[M,K] * W[N,K]^T + bias[N]
// A row-major lda=K, W row-major ldb=K, C row-major ldc=N.
// block = 256 threads, 64x64 tile, 4x4 microtile per thread.
// ---------------------------------------------------------------------------
__global__ __launch_bounds__(256) void gemm_nt_bias(
    const float* __restrict__ A, const float* __restrict__ W,
    const float* __restrict__ bias, float* __restrict__ C,
    int M, int N, int K)
{
    __shared__ float As[BK][BM + PAD];
    __shared__ float Bs[BK][BN + PAD];
    const int tid = threadIdx.x;
    const int bm = blockIdx.x * BM;
    const int bn = blockIdx.y * BN;
    const int tx = tid & 15;       // n-dir, 0..15
    const int ty = tid >> 4;       // m-dir, 0..15
    const int lr = tid >> 2;       // staging row 0..63
    const int lc = (tid & 3) << 2; // staging col 0,4,8,12

    float acc[4][4] = {};

    for (int k0 = 0; k0 < K; k0 += BK) {
        float4 av = *(const float4*)&A[(size_t)(bm + lr) * K + k0 + lc];
        float4 wv = *(const float4*)&W[(size_t)(bn + lr) * K + k0 + lc];
        __syncthreads();
        As[lc + 0][lr] = av.x; As[lc + 1][lr] = av.y;
        As[lc + 2][lr] = av.z; As[lc + 3][lr] = av.w;
        Bs[lc + 0][lr] = wv.x; Bs[lc + 1][lr] = wv.y;
        Bs[lc + 2][lr] = wv.z; Bs[lc + 3][lr] = wv.w;
        __syncthreads();
        #pragma unroll
        for (int kk = 0; kk < BK; ++kk) {
            float4 a4 = *(const float4*)&As[kk][ty * 4];
            float4 b4 = *(const float4*)&Bs[kk][tx * 4];
            float ar[4] = {a4.x, a4.y, a4.z, a4.w};
            float br[4] = {b4.x, b4.y, b4.z, b4.w};
            #pragma unroll
            for (int i = 0; i < 4; ++i)
                #pragma unroll
                for (int j = 0; j < 4; ++j)
                    acc[i][j] = fmaf(ar[i], br[j], acc[i][j]);
        }
    }

    const int n = bn + tx * 4;
    float4 bvec = *(const float4*)&bias[n];
    #pragma unroll
    for (int i = 0; i < 4; ++i) {
        int m = bm + ty * 4 + i;
        float4 o;
        o.x = acc[i][0] + bvec.x;
        o.y = acc[i][1] + bvec.y;
        o.z = acc[i][2] + bvec.z;
        o.w = acc[i][3] + bvec.w;
        *(float4*)&C[(size_t)m * N + n] = o;
    }
}

// ---------------------------------------------------------------------------
// Scores: per (b,h): S[q,kv] = scale * (qh . kh) + bias, written to attn.
// qh/kh are 64-wide slices of [B,L,D] buffers.  K = 64.
// ---------------------------------------------------------------------------
__global__ __launch_bounds__(256) void gemm_scores(
    const float* __restrict__ qn, const float* __restrict__ kn,
    const float* __restrict__ ls, const float* __restrict__ lb,
    float* __restrict__ attn)
{
    __shared__ float As[BK][BM + PAD];
    __shared__ float Bs[BK][BN + PAD];
    const int z = blockIdx.z;
    const int b = z >> 4, h = z & 15;
    const float* Ap = qn + (size_t)b * L_ * D_ + h * DH_;   // lda = D_
    const float* Bp = kn + (size_t)b * L_ * D_ + h * DH_;   // ldb = D_
    float* Cp = attn + (size_t)z * L_ * L_;                 // ldc = L_

    const int tid = threadIdx.x;
    const int bm = blockIdx.x * BM;
    const int bn = blockIdx.y * BN;
    const int tx = tid & 15;
    const int ty = tid >> 4;
    const int lr = tid >> 2;
    const int lc = (tid & 3) << 2;

    float acc[4][4] = {};

    for (int k0 = 0; k0 < DH_; k0 += BK) {
        float4 av = *(const float4*)&Ap[(size_t)(bm + lr) * D_ + k0 + lc];
        float4 wv = *(const float4*)&Bp[(size_t)(bn + lr) * D_ + k0 + lc];
        __syncthreads();
        As[lc + 0][lr] = av.x; As[lc + 1][lr] = av.y;
        As[lc + 2][lr] = av.z; As[lc + 3][lr] = av.w;
        Bs[lc + 0][lr] = wv.x; Bs[lc + 1][lr] = wv.y;
        Bs[lc + 2][lr] = wv.z; Bs[lc + 3][lr] = wv.w;
        __syncthreads();
        #pragma unroll
        for (int kk = 0; kk < BK; ++kk) {
            float4 a4 = *(const float4*)&As[kk][ty * 4];
            float4 b4 = *(const float4*)&Bs[kk][tx * 4];
            float ar[4] = {a4.x, a4.y, a4.z, a4.w};
            float br[4] = {b4.x, b4.y, b4.z, b4.w};
            #pragma unroll
            for (int i = 0; i < 4; ++i)
                #pragma unroll
                for (int j = 0; j < 4; ++j)
                    acc[i][j] = fmaf(ar[i], br[j], acc[i][j]);
        }
    }

    const float scale = expf(ls[0]);
    const float sbias = lb[0];
    const int n = bn + tx * 4;
    #pragma unroll
    for (int i = 0; i < 4; ++i) {
        int m = bm + ty * 4 + i;
        float4 o;
        o.x = acc[i][0] * scale + sbias;
        o.y = acc[i][1] * scale + sbias;
        o.z = acc[i][2] * scale + sbias;
        o.w = acc[i][3] * scale + sbias;
        *(float4*)&Cp[(size_t)m * L_ + n] = o;
    }
}

// ---------------------------------------------------------------------------
// PV: per (b,h): ctx[q,d] = sum_kv P[q,kv] * V[kv,d]  (NN GEMM, N = 64)
// ---------------------------------------------------------------------------
__global__ __launch_bounds__(256) void gemm_pv(
    const float* __restrict__ attn, const float* __restrict__ v,
    float* __restrict__ ctx)
{
    __shared__ float As[BK][BM + PAD];
    __shared__ float Bs[BK][BN + PAD];
    const int z = blockIdx.z;
    const int b = z >> 4, h = z & 15;
    const float* Ap = attn + (size_t)z * L_ * L_;           // lda = L_
    const float* Bp = v + (size_t)b * L_ * D_ + h * DH_;    // ldb = D_ ([K,64])
    float* Cp = ctx + (size_t)b * L_ * D_ + h * DH_;        // ldc = D_

    const int tid = threadIdx.x;
    const int bm = blockIdx.x * BM;   // bn = 0 (N = 64)
    const int tx = tid & 15;
    const int ty = tid >> 4;
    const int lr = tid >> 2;
    const int lc = (tid & 3) << 2;
    const int kr = tid >> 4;          // 0..15 (B-tile k row)
    const int nc = (tid & 15) << 2;   // 0..60 (B-tile n col)

    float acc[4][4] = {};

    for (int k0 = 0; k0 < L_; k0 += BK) {
        float4 av = *(const float4*)&Ap[(size_t)(bm + lr) * L_ + k0 + lc];
        float4 bv = *(const float4*)&Bp[(size_t)(k0 + kr) * D_ + nc];
        __syncthreads();
        As[lc + 0][lr] = av.x; As[lc + 1][lr] = av.y;
        As[lc + 2][lr] = av.z; As[lc + 3][lr] = av.w;
        *(float4*)&Bs[kr][nc] = bv;
        __syncthreads();
        #pragma unroll
        for (int kk = 0; kk < BK; ++kk) {
            float4 a4 = *(const float4*)&As[kk][ty * 4];
            float4 b4 = *(const float4*)&Bs[kk][tx * 4];
            float ar[4] = {a4.x, a4.y, a4.z, a4.w};
            float br[4] = {b4.x, b4.y, b4.z, b4.w};
            #pragma unroll
            for (int i = 0; i < 4; ++i)
                #pragma unroll
                for (int j = 0; j < 4; ++j)
                    acc[i][j] = fmaf(ar[i], br[j], acc[i][j]);
        }
    }

    const int n = tx * 4;
    #pragma unroll
    for (int i = 0; i < 4; ++i) {
        int m = bm + ty * 4 + i;
        float4 o = {acc[i][0], acc[i][1], acc[i][2], acc[i][3]};
        *(float4*)&Cp[(size_t)m * D_ + n] = o;
    }
}

// ---------------------------------------------------------------------------
// In-place row L2 normalization over D_ = 1024 (one block per row).
// ---------------------------------------------------------------------------
__global__ __launch_bounds__(256) void l2norm_rows(float* __restrict__ x)
{
    float* row = x + (size_t)blockIdx.x * D_;
    const int tid = threadIdx.x;
    float4 v = *(const float4*)&row[tid * 4];
    float ss = v.x * v.x + v.y * v.y + v.z * v.z + v.w * v.w;
    #pragma unroll
    for (int off = 32; off >= 1; off >>= 1)
        ss += __shfl_xor(ss, off);
    __shared__ float red[4];
    const int lane = tid & 63, wid = tid >> 6;
    if (lane == 0) red[wid] = ss;
    __syncthreads();
    ss = red[0] + red[1] + red[2] + red[3];
    const float inv = rsqrtf(ss);
    v.x *= inv; v.y *= inv; v.z *= inv; v.w *= inv;
    *(float4*)&row[tid * 4] = v;
}

// ---------------------------------------------------------------------------
// In-place softmax over rows of length L_ = 2048 (one block per row).
// ---------------------------------------------------------------------------
__global__ __launch_bounds__(256) void softmax_rows(float* __restrict__ attn)
{
    float* row = attn + (size_t)blockIdx.x * L_;
    const int tid = threadIdx.x;
    float4 v0 = *(const float4*)&row[tid * 8];
    float4 v1 = *(const float4*)&row[tid * 8 + 4];
    float x[8] = {v0.x, v0.y, v0.z, v0.w, v1.x, v1.y, v1.z, v1.w};

    float mx = x[0];
    #pragma unroll
    for (int i = 1; i < 8; ++i) mx = fmaxf(mx, x[i]);
    #pragma unroll
    for (int off = 32; off >= 1; off >>= 1)
        mx = fmaxf(mx, __shfl_xor(mx, off));
    __shared__ float redm[4];
    const int lane = tid & 63, wid = tid >> 6;
    if (lane == 0) redm[wid] = mx;
    __syncthreads();
    mx = fmaxf(fmaxf(redm[0], redm[1]), fmaxf(redm[2], redm[3]));

    float s = 0.f;
    #pragma unroll
    for (int i = 0; i < 8; ++i) { x[i] = __expf(x[i] - mx); s += x[i]; }
    #pragma unroll
    for (int off = 32; off >= 1; off >>= 1)
        s += __shfl_xor(s, off);
    __shared__ float reds[4];
    if (lane == 0) reds[wid] = s;
    __syncthreads();
    s = reds[0] + reds[1] + reds[2] + reds[3];
    const float inv = 1.0f / s;

    v0.x = x[0] * inv; v0.y = x[1] * inv; v0.z = x[2] * inv; v0.w = x[3] * inv;
    v1.x = x[4] * inv; v1.y = x[5] * inv; v1.z = x[6] * inv; v1.w = x[7] * inv;
    *(float4*)&row[tid * 8] = v0;
    *(float4*)&row[tid * 8 + 4] = v1;
}

// ---------------------------------------------------------------------------
extern "C" void kernel_launch(void* const* d_in, const int* in_sizes, int n_in,
                              void* d_out, int out_size, void* d_ws, size_t ws_size,
                              hipStream_t stream)
{
    const float* query = (const float*)d_in[0];
    const float* key_  = (const float*)d_in[1];
    const float* value = (const float*)d_in[2];
    const float* ls    = (const float*)d_in[3];
    const float* lb    = (const float*)d_in[4];
    const float* Wq    = (const float*)d_in[5];
    const float* bq    = (const float*)d_in[6];
    const float* Wk    = (const float*)d_in[7];
    const float* bk    = (const float*)d_in[8];
    const float* Wv    = (const float*)d_in[9];
    const float* bv    = (const float*)d_in[10];
    const float* Wo    = (const float*)d_in[11];
    const float* bo    = (const float*)d_in[12];

    float* out  = (float*)d_out;                     // [B, L, D]
    float* attn = out + (size_t)M_TOT * D_;          // [B, H, L, L]

    float* ws = (float*)d_ws;
    float* q   = ws;                                  // 16 MB
    float* k   = q + (size_t)M_TOT * D_;              // 16 MB
    float* v   = k + (size_t)M_TOT * D_;              // 16 MB
    float* ctx = q;                                   // reuse q (dead after scores)

    dim3 blk(256);
    dim3 gproj(M_TOT / BM, D_ / BN);

    gemm_nt_bias<<<gproj, blk, 0, stream>>>(query, Wq, bq, q, M_TOT, D_, D_);
    gemm_nt_bias<<<gproj, blk, 0, stream>>>(key_,  Wk, bk, k, M_TOT, D_, D_);
    gemm_nt_bias<<<gproj, blk, 0, stream>>>(value, Wv, bv, v, M_TOT, D_, D_);

    l2norm_rows<<<dim3(M_TOT), blk, 0, stream>>>(q);
    l2norm_rows<<<dim3(M_TOT), blk, 0, stream>>>(k);

    gemm_scores<<<dim3(L_ / BM, L_ / BN, B_ * H_), blk, 0, stream>>>(q, k, ls, lb, attn);

    softmax_rows<<<dim3(B_ * H_ * L_), blk, 0, stream>>>(attn);

    gemm_pv<<<dim3(L_ / BM, 1, B_ * H_), blk, 0, stream>>>(attn, v, ctx);

    gemm_nt_bias<<<gproj, blk, 0, stream>>>(ctx, Wo, bo, out, M_TOT, D_, D_);
}